// Round 1
// baseline (577.232 us; speedup 1.0000x reference)
//
#include <hip/hip_runtime.h>
#include <cstddef>

#define IN_CH 1024
#define NT    81
#define KGRID 7
#define NBINS 49
#define HH    100
#define WW    100
#define NPIX  (HH*WW)
#define NREG  1024

// ---------------- transpose x (C, H*W) -> xt (H*W, C) for coalesced gathers ---------
__global__ __launch_bounds__(256) void xpose_kernel(const float* __restrict__ x,
                                                    float* __restrict__ xt) {
    __shared__ float tile[32][33];
    const int p0 = blockIdx.x * 32;
    const int c0 = blockIdx.y * 32;
    const int tx = threadIdx.x;   // 0..31
    const int ty = threadIdx.y;   // 0..7
#pragma unroll
    for (int k = 0; k < 32; k += 8) {
        const int p = p0 + tx;
        if (p < NPIX) tile[ty + k][tx] = x[(size_t)(c0 + ty + k) * NPIX + p];
    }
    __syncthreads();
#pragma unroll
    for (int k = 0; k < 32; k += 8) {
        const int p = p0 + ty + k;
        if (p < NPIX) xt[(size_t)p * IN_CH + (c0 + tx)] = tile[tx][ty + k];
    }
}

// ---------------- fused PSROIAlign + 1x1-conv head -----------------------------------
// grid: 49 bins x 16 region-groups (64 regions each). 256 threads.
// Per chunk of 32 channels: stage W[81][32] and g[32][64] in LDS, then
// register-tiled fp32 GEMM: thread = (ri = tid&15 -> 4 consecutive regions,
// tq = tid>>4 -> 6 consecutive targets). Partial scores atomicAdd'ed to out.
template <bool XPOSED>
__global__ __launch_bounds__(256) void psroi_kernel(
    const float* __restrict__ xsrc,     // XPOSED ? (NPIX, C) : (C, NPIX)
    const float* __restrict__ regions,  // (1024, 4)
    const float* __restrict__ conv_w,   // (3969, 1024)
    const float* __restrict__ conv_b,   // (3969,)
    float* __restrict__ out)            // (1024, 81), pre-zeroed
{
    __shared__ float w_lds[32 * 96];    // [c][t], t padded 81->96, zero-filled
    __shared__ float g_lds[32 * 64];    // [c][r]
    __shared__ int   rowoff[64][4];     // y*WW, 4 row taps per region
    __shared__ float roww[64][4];       // row weights (x 1/196 folded in)
    __shared__ int   colidx[64][4];
    __shared__ float colw[64][4];

    const int tid = threadIdx.x;
    const int bin = blockIdx.x >> 4;    // 0..48
    const int rg  = blockIdx.x & 15;    // 0..15
    const int u = bin / KGRID, v = bin % KGRID;
    const int r0 = rg * 64;

    // ---- phase 1: region geometry (one thread per region) ----
    if (tid < 64) {
        const float4 reg = *(const float4*)(regions + (size_t)(r0 + tid) * 4);
        const float top  = (reg.x - reg.z * 0.5f) * (float)HH;
        const float left = (reg.y - reg.w * 0.5f) * (float)WW;
        const float bh = reg.z * ((float)HH / (float)KGRID);
        const float bw = reg.w * ((float)WW / (float)KGRID);
        const float scale = 1.0f / 196.0f;  // 1/(K*K) * 1/(S*S)
#pragma unroll
        for (int s = 0; s < 2; s++) {
            const float off = (s + 0.5f) * 0.5f;  // (s+0.5)/S
            // rows (uses u, bh)
            float yy = top + ((float)u + off) * bh;
            yy = fminf(fmaxf(yy, 0.0f), (float)(HH - 1));
            const float y0f = floorf(yy);
            const int y0 = (int)y0f;
            const int y1 = min(y0 + 1, HH - 1);
            const float wy1 = yy - y0f;
            rowoff[tid][2 * s]     = y0 * WW;
            rowoff[tid][2 * s + 1] = y1 * WW;
            roww[tid][2 * s]       = (1.0f - wy1) * scale;
            roww[tid][2 * s + 1]   = wy1 * scale;
            // cols (uses v, bw)
            float xx = left + ((float)v + off) * bw;
            xx = fminf(fmaxf(xx, 0.0f), (float)(WW - 1));
            const float x0f = floorf(xx);
            const int x0 = (int)x0f;
            const int x1 = min(x0 + 1, WW - 1);
            const float wx1 = xx - x0f;
            colidx[tid][2 * s]     = x0;
            colidx[tid][2 * s + 1] = x1;
            colw[tid][2 * s]       = 1.0f - wx1;
            colw[tid][2 * s + 1]   = wx1;
        }
    }

    const int ri = tid & 15;   // region quad: regions r0 + ri*4 .. +3
    const int tq = tid >> 4;   // target group: targets tq*6 .. +5
    const int rb = tid >> 2;   // build phase: region 0..63
    const int cq = tid & 3;    // build phase: channel octet within chunk

    float acc[4][6];
#pragma unroll
    for (int m = 0; m < 4; m++)
#pragma unroll
        for (int k = 0; k < 6; k++) acc[m][k] = 0.0f;

    for (int chunk = 0; chunk < IN_CH / 32; chunk++) {
        const int c0 = chunk * 32;
        __syncthreads();  // prev-iteration FMA reads done before LDS overwrite

        // ---- stage W slice: w_lds[c][t] = conv_w[(t*49+bin)][c0+c], 0 for t>=81 ----
#pragma unroll
        for (int it = 0; it < 12; it++) {         // 12*256 == 96*32
            const int idx = it * 256 + tid;
            const int t = idx >> 5;
            const int c = idx & 31;
            float val = 0.0f;
            if (t < NT) val = conv_w[(size_t)(t * NBINS + bin) * IN_CH + c0 + c];
            w_lds[c * 96 + t] = val;
        }

        // ---- build g: thread (rb, cq) accumulates 8 channels over 16 bilinear taps ----
        const int cbase = c0 + cq * 8;
        float g8[8];
#pragma unroll
        for (int cc = 0; cc < 8; cc++) g8[cc] = 0.0f;
#pragma unroll
        for (int i = 0; i < 4; i++) {
            const int   ro = rowoff[rb][i];
            const float wy = roww[rb][i];
#pragma unroll
            for (int j = 0; j < 4; j++) {
                const int pix = ro + colidx[rb][j];
                const float w = wy * colw[rb][j];
                if (XPOSED) {
                    const float4* p = (const float4*)(xsrc + (size_t)pix * IN_CH + cbase);
                    const float4 a = p[0];
                    const float4 b = p[1];
                    g8[0] += w * a.x; g8[1] += w * a.y; g8[2] += w * a.z; g8[3] += w * a.w;
                    g8[4] += w * b.x; g8[5] += w * b.y; g8[6] += w * b.z; g8[7] += w * b.w;
                } else {
#pragma unroll
                    for (int cc = 0; cc < 8; cc++)
                        g8[cc] += w * xsrc[(size_t)(cbase + cc) * NPIX + pix];
                }
            }
        }
#pragma unroll
        for (int cc = 0; cc < 8; cc++)
            g_lds[(cq * 8 + cc) * 64 + rb] = g8[cc];

        __syncthreads();

        // ---- register-tiled fp32 GEMM: 24 FMA per channel per thread ----
#pragma unroll 4
        for (int c = 0; c < 32; c++) {
            float wv[6];
#pragma unroll
            for (int k = 0; k < 6; k++) wv[k] = w_lds[c * 96 + tq * 6 + k];
            const float4 gq = *(const float4*)&g_lds[c * 64 + ri * 4];
            const float gm[4] = {gq.x, gq.y, gq.z, gq.w};
#pragma unroll
            for (int m = 0; m < 4; m++)
#pragma unroll
                for (int k = 0; k < 6; k++) acc[m][k] += gm[m] * wv[k];
        }
    }

    // ---- write out partials (49-way accumulation across bin-blocks) ----
    const float invK2 = 1.0f / 49.0f;
#pragma unroll
    for (int k = 0; k < 6; k++) {
        const int t = tq * 6 + k;
        if (t < NT) {
            const float bterm = conv_b[t * NBINS + bin] * invK2;
#pragma unroll
            for (int m = 0; m < 4; m++) {
                const int r = r0 + ri * 4 + m;
                atomicAdd(&out[(size_t)r * NT + t], acc[m][k] + bterm);
            }
        }
    }
}

extern "C" void kernel_launch(void* const* d_in, const int* in_sizes, int n_in,
                              void* d_out, int out_size, void* d_ws, size_t ws_size,
                              hipStream_t stream) {
    const float* x       = (const float*)d_in[0];   // (1024, 100, 100)
    const float* regions = (const float*)d_in[1];   // (1024, 4)
    const float* conv_w  = (const float*)d_in[2];   // (3969, 1024)
    const float* conv_b  = (const float*)d_in[3];   // (3969,)
    float* out = (float*)d_out;                     // (1024, 81)

    // out is re-poisoned to 0xAA before every timed launch; we accumulate with atomics
    hipMemsetAsync(out, 0, (size_t)out_size * sizeof(float), stream);

    const size_t xt_bytes = (size_t)NPIX * IN_CH * sizeof(float);
    const dim3 mainGrid(NBINS * 16);

    if (ws_size >= xt_bytes) {
        float* xt = (float*)d_ws;
        const dim3 tGrid((NPIX + 31) / 32, IN_CH / 32);
        const dim3 tBlk(32, 8);
        xpose_kernel<<<tGrid, tBlk, 0, stream>>>(x, xt);
        psroi_kernel<true><<<mainGrid, 256, 0, stream>>>(xt, regions, conv_w, conv_b, out);
    } else {
        psroi_kernel<false><<<mainGrid, 256, 0, stream>>>(x, regions, conv_w, conv_b, out);
    }
}

// Round 2
// 312.494 us; speedup vs baseline: 1.8472x; 1.8472x over previous
//
#include <hip/hip_runtime.h>
#include <cstddef>

#define IN_CH 1024
#define NT    81
#define NTP   96
#define KGRID 7
#define NBINS 49
#define HH    100
#define WW    100
#define NPIX  (HH*WW)
#define NREG  1024
#define PTILE 256
#define NPT   40

typedef unsigned short ushortT;
typedef short bf16x8 __attribute__((ext_vector_type(8)));
typedef float f32x4  __attribute__((ext_vector_type(4)));

static __device__ __forceinline__ unsigned short f2bf(float f) {
    unsigned int u = __builtin_bit_cast(unsigned int, f);
    return (unsigned short)((u + 0x7fffu + ((u >> 16) & 1u)) >> 16);
}

// ---------- prep 1: x (C, P) fp32 -> xbT (P, C) bf16 -------------------------------
__global__ __launch_bounds__(256) void prep_x(const float* __restrict__ x,
                                              ushortT* __restrict__ xbT) {
    __shared__ float tile[64][33];
    const int tid = threadIdx.x;
    const int p0 = blockIdx.x * 64;
    const int c0 = blockIdx.y * 32;
    const int pl = tid & 63;
    const int cg = tid >> 6;      // 0..3 -> 8 channels each
#pragma unroll
    for (int cc = 0; cc < 8; ++cc) {
        const int c = cg * 8 + cc;
        const int p = p0 + pl;
        tile[pl][c] = (p < NPIX) ? x[(size_t)(c0 + c) * NPIX + p] : 0.0f;
    }
    __syncthreads();
#pragma unroll
    for (int ph = 0; ph < 4; ++ph) {
        const int plr = ph * 16 + (tid >> 4);
        const int p = p0 + plr;
        const int c = (tid & 15) * 2;
        if (p < NPIX) {
            const unsigned int pk = (unsigned int)f2bf(tile[plr][c]) |
                                    ((unsigned int)f2bf(tile[plr][c + 1]) << 16);
            *(unsigned int*)(xbT + (size_t)p * IN_CH + c0 + c) = pk;
        }
    }
}

// ---------- prep 2: conv_w (3969,1024) fp32 -> Wr (49*96,1024) bf16, bin-major -----
__global__ __launch_bounds__(256) void prep_w(const float* __restrict__ conv_w,
                                              ushortT* __restrict__ Wr) {
    const int row = blockIdx.x;           // bin*96 + t
    const int bin = row / NTP;
    const int t   = row - bin * NTP;
    const int c   = threadIdx.x * 4;
    unsigned int pk0 = 0, pk1 = 0;
    if (t < NT) {
        const float4 v = *(const float4*)(conv_w + ((size_t)(t * NBINS + bin)) * IN_CH + c);
        pk0 = (unsigned int)f2bf(v.x) | ((unsigned int)f2bf(v.y) << 16);
        pk1 = (unsigned int)f2bf(v.z) | ((unsigned int)f2bf(v.w) << 16);
    }
    uint2 pk; pk.x = pk0; pk.y = pk1;
    *(uint2*)(Wr + (size_t)row * IN_CH + c) = pk;
}

// ---------- GEMM: sm[bin][pix][96] bf16 = xbT(P,K) @ Wr(bin)(96,K)^T ----------------
// block = (bin, 256-pix tile), 256 thr / 4 waves; wave owns 64 pix x 96 t.
__global__ __launch_bounds__(256) void gemm_sm(const ushortT* __restrict__ xbT,
                                               const ushortT* __restrict__ Wr,
                                               ushortT* __restrict__ sm) {
    __shared__ ushortT a_lds[PTILE * 32];   // [p][k]
    __shared__ ushortT b_lds[NTP * 32];     // [t][k]
    const int tid  = threadIdx.x;
    const int bin  = blockIdx.x;
    const int p0   = blockIdx.y * PTILE;
    const int lane = tid & 63;
    const int w    = tid >> 6;
    const int arow = tid >> 2;              // A-stage: row in 64-group
    const int acol = (tid & 3) * 8;         // 8 bf16 = 16B
    const int m_lane = lane & 15;
    const int k0     = (lane >> 4) * 8;
    const size_t wbase = (size_t)bin * NTP * IN_CH;

    f32x4 acc[4][6];
#pragma unroll
    for (int mt = 0; mt < 4; ++mt)
#pragma unroll
        for (int nt = 0; nt < 6; ++nt) acc[mt][nt] = (f32x4){0.f, 0.f, 0.f, 0.f};

    for (int kc = 0; kc < IN_CH / 32; ++kc) {
        const int c0 = kc * 32;
        __syncthreads();
        // stage A: 256 pix rows x 32 ch
#pragma unroll
        for (int pp = 0; pp < 4; ++pp) {
            const int r = pp * 64 + arow;
            int prow = p0 + r; if (prow > NPIX - 1) prow = NPIX - 1;
            const uint4 v = *(const uint4*)(xbT + (size_t)prow * IN_CH + c0 + acol);
            *(uint4*)(a_lds + r * 32 + acol) = v;
        }
        // stage B: 96 t rows x 32 ch = 384 16B chunks
        for (int idx = tid; idx < 384; idx += 256) {
            const int r = idx >> 2, q = (idx & 3) * 8;
            const uint4 v = *(const uint4*)(Wr + wbase + (size_t)r * IN_CH + c0 + q);
            *(uint4*)(b_lds + r * 32 + q) = v;
        }
        __syncthreads();
        bf16x8 af[4], bfr[6];
#pragma unroll
        for (int mt = 0; mt < 4; ++mt)
            af[mt] = *(const bf16x8*)(a_lds + (w * 64 + mt * 16 + m_lane) * 32 + k0);
#pragma unroll
        for (int nt = 0; nt < 6; ++nt)
            bfr[nt] = *(const bf16x8*)(b_lds + (nt * 16 + m_lane) * 32 + k0);
#pragma unroll
        for (int mt = 0; mt < 4; ++mt)
#pragma unroll
            for (int nt = 0; nt < 6; ++nt)
                acc[mt][nt] = __builtin_amdgcn_mfma_f32_16x16x32_bf16(af[mt], bfr[nt], acc[mt][nt], 0, 0, 0);
    }

    // epilogue: C row = pix, col = t. Store bf16 to sm[bin][pix][96].
    const int prow_base = p0 + w * 64 + (lane >> 4) * 4;
    const int t_lane = lane & 15;
    ushortT* op = sm + ((size_t)bin * NPIX + prow_base) * NTP + t_lane;
#pragma unroll
    for (int mt = 0; mt < 4; ++mt) {
#pragma unroll
        for (int rg = 0; rg < 4; ++rg) {
            const int p = prow_base + mt * 16 + rg;
            if (p < NPIX) {
#pragma unroll
                for (int nt = 0; nt < 6; ++nt)
                    op[(size_t)(mt * 16 + rg) * NTP + nt * 16] = f2bf(acc[mt][nt][rg]);
            }
        }
    }
}

// ---------- pooling: one block per region, 784 weighted taps of 96 bf16 -------------
__global__ __launch_bounds__(256) void pool_kernel(const ushortT* __restrict__ sm,
                                                   const float* __restrict__ regions,
                                                   const float* __restrict__ conv_b,
                                                   float* __restrict__ out) {
    __shared__ int   pofs[784];
    __shared__ float pw[784];
    __shared__ int   rowo[28]; __shared__ float roww[28];
    __shared__ int   coli[28]; __shared__ float colw[28];
    __shared__ float part[4][96];
    const int tid = threadIdx.x;
    const int r = blockIdx.x;

    if (tid < 28) {
        const float4 reg = *(const float4*)(regions + (size_t)r * 4);
        const float top = (reg.x - reg.z * 0.5f) * (float)HH;
        const float bh  = reg.z * ((float)HH / (float)KGRID);
        const int u = tid >> 2, i = tid & 3;
        const int s = i >> 1, hi = i & 1;
        float y = top + ((float)u + ((float)s + 0.5f) * 0.5f) * bh;
        y = fminf(fmaxf(y, 0.0f), (float)(HH - 1));
        const float y0f = floorf(y);
        const int y0 = (int)y0f;
        const float wy1 = y - y0f;
        rowo[tid] = (hi ? min(y0 + 1, HH - 1) : y0) * WW;
        roww[tid] = hi ? wy1 : (1.0f - wy1);
    } else if (tid >= 32 && tid < 60) {
        const float4 reg = *(const float4*)(regions + (size_t)r * 4);
        const float left = (reg.y - reg.w * 0.5f) * (float)WW;
        const float bw   = reg.w * ((float)WW / (float)KGRID);
        const int idx = tid - 32;
        const int v = idx >> 2, j = idx & 3;
        const int s = j >> 1, hi = j & 1;
        float xx = left + ((float)v + ((float)s + 0.5f) * 0.5f) * bw;
        xx = fminf(fmaxf(xx, 0.0f), (float)(WW - 1));
        const float x0f = floorf(xx);
        const int x0 = (int)x0f;
        const float wx1 = xx - x0f;
        coli[idx] = hi ? min(x0 + 1, WW - 1) : x0;
        colw[idx] = hi ? wx1 : (1.0f - wx1);
    }
    __syncthreads();
    for (int tt = tid; tt < 784; tt += 256) {
        const int bin = tt >> 4, tap = tt & 15;
        const int u = bin / KGRID, v = bin - u * KGRID;
        const int i = tap >> 2, j = tap & 3;
        pofs[tt] = (bin * NPIX + rowo[u * 4 + i] + coli[v * 4 + j]) * NTP;
        pw[tt]   = roww[u * 4 + i] * colw[v * 4 + j] * (1.0f / 196.0f);
    }
    __syncthreads();
    const int lane = tid & 63, w = tid >> 6;
    if (lane < 48) {
        float accx = 0.f, accy = 0.f;
        const int l2 = lane * 2;
#pragma unroll 4
        for (int tt = w; tt < 784; tt += 4) {
            const unsigned int v = *(const unsigned int*)(sm + pofs[tt] + l2);
            const float wt = pw[tt];
            accx += wt * __builtin_bit_cast(float, v << 16);
            accy += wt * __builtin_bit_cast(float, v & 0xffff0000u);
        }
        part[w][l2] = accx; part[w][l2 + 1] = accy;
    }
    __syncthreads();
    if (tid < NT) {
        const float sv = part[0][tid] + part[1][tid] + part[2][tid] + part[3][tid];
        float b = 0.f;
        for (int bin = 0; bin < NBINS; ++bin) b += conv_b[tid * NBINS + bin];
        out[(size_t)r * NT + tid] = sv + b * (1.0f / (float)NBINS);
    }
}

// =======================  fallback path (round-1 kernel)  ==========================
__global__ __launch_bounds__(256) void xpose_kernel(const float* __restrict__ x,
                                                    float* __restrict__ xt) {
    __shared__ float tile[32][33];
    const int p0 = blockIdx.x * 32;
    const int c0 = blockIdx.y * 32;
    const int tx = threadIdx.x;
    const int ty = threadIdx.y;
#pragma unroll
    for (int k = 0; k < 32; k += 8) {
        const int p = p0 + tx;
        if (p < NPIX) tile[ty + k][tx] = x[(size_t)(c0 + ty + k) * NPIX + p];
    }
    __syncthreads();
#pragma unroll
    for (int k = 0; k < 32; k += 8) {
        const int p = p0 + ty + k;
        if (p < NPIX) xt[(size_t)p * IN_CH + (c0 + tx)] = tile[tx][ty + k];
    }
}

template <bool XPOSED>
__global__ __launch_bounds__(256) void psroi_kernel(
    const float* __restrict__ xsrc, const float* __restrict__ regions,
    const float* __restrict__ conv_w, const float* __restrict__ conv_b,
    float* __restrict__ out) {
    __shared__ float w_lds[32 * 96];
    __shared__ float g_lds[32 * 64];
    __shared__ int   rowoff[64][4];
    __shared__ float rowwf[64][4];
    __shared__ int   colidx[64][4];
    __shared__ float colwf[64][4];
    const int tid = threadIdx.x;
    const int bin = blockIdx.x >> 4;
    const int rg  = blockIdx.x & 15;
    const int u = bin / KGRID, v = bin % KGRID;
    const int r0 = rg * 64;
    if (tid < 64) {
        const float4 reg = *(const float4*)(regions + (size_t)(r0 + tid) * 4);
        const float top  = (reg.x - reg.z * 0.5f) * (float)HH;
        const float left = (reg.y - reg.w * 0.5f) * (float)WW;
        const float bh = reg.z * ((float)HH / (float)KGRID);
        const float bw = reg.w * ((float)WW / (float)KGRID);
        const float scale = 1.0f / 196.0f;
#pragma unroll
        for (int s = 0; s < 2; s++) {
            const float off = (s + 0.5f) * 0.5f;
            float yy = top + ((float)u + off) * bh;
            yy = fminf(fmaxf(yy, 0.0f), (float)(HH - 1));
            const float y0f = floorf(yy);
            const int y0 = (int)y0f;
            const float wy1 = yy - y0f;
            rowoff[tid][2 * s] = y0 * WW;
            rowoff[tid][2 * s + 1] = min(y0 + 1, HH - 1) * WW;
            rowwf[tid][2 * s] = (1.0f - wy1) * scale;
            rowwf[tid][2 * s + 1] = wy1 * scale;
            float xx = left + ((float)v + off) * bw;
            xx = fminf(fmaxf(xx, 0.0f), (float)(WW - 1));
            const float x0f = floorf(xx);
            const int x0 = (int)x0f;
            const float wx1 = xx - x0f;
            colidx[tid][2 * s] = x0;
            colidx[tid][2 * s + 1] = min(x0 + 1, WW - 1);
            colwf[tid][2 * s] = 1.0f - wx1;
            colwf[tid][2 * s + 1] = wx1;
        }
    }
    const int ri = tid & 15, tq = tid >> 4, rb = tid >> 2, cq = tid & 3;
    float acc[4][6];
#pragma unroll
    for (int m = 0; m < 4; m++)
#pragma unroll
        for (int k = 0; k < 6; k++) acc[m][k] = 0.0f;
    for (int chunk = 0; chunk < IN_CH / 32; chunk++) {
        const int c0 = chunk * 32;
        __syncthreads();
#pragma unroll
        for (int it = 0; it < 12; it++) {
            const int idx = it * 256 + tid;
            const int t = idx >> 5, c = idx & 31;
            float val = 0.0f;
            if (t < NT) val = conv_w[(size_t)(t * NBINS + bin) * IN_CH + c0 + c];
            w_lds[c * 96 + t] = val;
        }
        const int cbase = c0 + cq * 8;
        float g8[8];
#pragma unroll
        for (int cc = 0; cc < 8; cc++) g8[cc] = 0.0f;
#pragma unroll
        for (int i = 0; i < 4; i++) {
            const int ro = rowoff[rb][i];
            const float wy = rowwf[rb][i];
#pragma unroll
            for (int j = 0; j < 4; j++) {
                const int pix = ro + colidx[rb][j];
                const float wv = wy * colwf[rb][j];
                if (XPOSED) {
                    const float4* p = (const float4*)(xsrc + (size_t)pix * IN_CH + cbase);
                    const float4 a = p[0]; const float4 b = p[1];
                    g8[0] += wv * a.x; g8[1] += wv * a.y; g8[2] += wv * a.z; g8[3] += wv * a.w;
                    g8[4] += wv * b.x; g8[5] += wv * b.y; g8[6] += wv * b.z; g8[7] += wv * b.w;
                } else {
#pragma unroll
                    for (int cc = 0; cc < 8; cc++)
                        g8[cc] += wv * xsrc[(size_t)(cbase + cc) * NPIX + pix];
                }
            }
        }
#pragma unroll
        for (int cc = 0; cc < 8; cc++) g_lds[(cq * 8 + cc) * 64 + rb] = g8[cc];
        __syncthreads();
#pragma unroll 4
        for (int c = 0; c < 32; c++) {
            float wv[6];
#pragma unroll
            for (int k = 0; k < 6; k++) wv[k] = w_lds[c * 96 + tq * 6 + k];
            const float4 gq = *(const float4*)&g_lds[c * 64 + ri * 4];
            const float gm[4] = {gq.x, gq.y, gq.z, gq.w};
#pragma unroll
            for (int m = 0; m < 4; m++)
#pragma unroll
                for (int k = 0; k < 6; k++) acc[m][k] += gm[m] * wv[k];
        }
    }
    const float invK2 = 1.0f / 49.0f;
#pragma unroll
    for (int k = 0; k < 6; k++) {
        const int t = tq * 6 + k;
        if (t < NT) {
            const float bterm = conv_b[t * NBINS + bin] * invK2;
#pragma unroll
            for (int m = 0; m < 4; m++) {
                const int rr = r0 + ri * 4 + m;
                atomicAdd(&out[(size_t)rr * NT + t], acc[m][k] + bterm);
            }
        }
    }
}

extern "C" void kernel_launch(void* const* d_in, const int* in_sizes, int n_in,
                              void* d_out, int out_size, void* d_ws, size_t ws_size,
                              hipStream_t stream) {
    const float* x       = (const float*)d_in[0];
    const float* regions = (const float*)d_in[1];
    const float* conv_w  = (const float*)d_in[2];
    const float* conv_b  = (const float*)d_in[3];
    float* out = (float*)d_out;

    const size_t sz_xbT = (size_t)NPIX * IN_CH * 2;          // 20,480,000
    const size_t sz_Wr  = (size_t)NBINS * NTP * IN_CH * 2;   //  9,633,792
    const size_t sz_sm  = (size_t)NBINS * NPIX * NTP * 2;    // 94,080,000
    const size_t need   = sz_xbT + sz_Wr + sz_sm;

    if (ws_size >= need) {
        ushortT* xbT = (ushortT*)d_ws;
        ushortT* Wr  = (ushortT*)((char*)d_ws + sz_xbT);
        ushortT* sm  = (ushortT*)((char*)d_ws + sz_xbT + sz_Wr);
        prep_x<<<dim3((NPIX + 63) / 64, IN_CH / 32), 256, 0, stream>>>(x, xbT);
        prep_w<<<dim3(NBINS * NTP), 256, 0, stream>>>(conv_w, Wr);
        gemm_sm<<<dim3(NBINS, NPT), 256, 0, stream>>>(xbT, Wr, sm);
        pool_kernel<<<dim3(NREG), 256, 0, stream>>>(sm, regions, conv_b, out);
    } else {
        hipMemsetAsync(out, 0, (size_t)out_size * sizeof(float), stream);
        const size_t xt_bytes = (size_t)NPIX * IN_CH * sizeof(float);
        const dim3 mainGrid(NBINS * 16);
        if (ws_size >= xt_bytes) {
            float* xt = (float*)d_ws;
            xpose_kernel<<<dim3((NPIX + 31) / 32, IN_CH / 32), dim3(32, 8), 0, stream>>>(x, xt);
            psroi_kernel<true><<<mainGrid, 256, 0, stream>>>(xt, regions, conv_w, conv_b, out);
        } else {
            psroi_kernel<false><<<mainGrid, 256, 0, stream>>>(x, regions, conv_w, conv_b, out);
        }
    }
}

// Round 3
// 242.038 us; speedup vs baseline: 2.3849x; 1.2911x over previous
//
#include <hip/hip_runtime.h>
#include <cstddef>

#define IN_CH 1024
#define NT    81
#define KGRID 7
#define NBINS 49
#define HH    100
#define WW    100
#define NPIX  (HH*WW)
#define NREG  1024
#define COLB  82            // padded targets per bin (even -> uint-aligned pool reads)
#define NCOL  (NBINS*COLB)  // 4018 real columns
#define NPADW 4096          // 32 N-tiles of 128
#define SMSTR NCOL          // sm row stride (ushort elements)

typedef unsigned short ushortT;
typedef short bf16x8 __attribute__((ext_vector_type(8)));
typedef float f32x4  __attribute__((ext_vector_type(4)));

static __device__ __forceinline__ unsigned short f2bf(float f) {
    unsigned int u = __builtin_bit_cast(unsigned int, f);
    return (unsigned short)((u + 0x7fffu + ((u >> 16) & 1u)) >> 16);
}

// async global->LDS, 16B per lane; LDS dest = wave-uniform base + lane*16
static __device__ __forceinline__ void gld_lds16(const ushortT* g, ushortT* l) {
    __builtin_amdgcn_global_load_lds(
        (__attribute__((address_space(1))) void*)(unsigned long long)(uintptr_t)g,
        (__attribute__((address_space(3))) void*)(unsigned int)(unsigned long long)(uintptr_t)l,
        16, 0, 0);
}

// ---------- prep 1: x (C, P) fp32 -> xbT (P, C) bf16 -------------------------------
__global__ __launch_bounds__(256) void prep_x(const float* __restrict__ x,
                                              ushortT* __restrict__ xbT) {
    __shared__ float tile[64][33];
    const int tid = threadIdx.x;
    const int p0 = blockIdx.x * 64;
    const int c0 = blockIdx.y * 32;
    const int pl = tid & 63;
    const int cg = tid >> 6;
#pragma unroll
    for (int cc = 0; cc < 8; ++cc) {
        const int c = cg * 8 + cc;
        const int p = p0 + pl;
        tile[pl][c] = (p < NPIX) ? x[(size_t)(c0 + c) * NPIX + p] : 0.0f;
    }
    __syncthreads();
#pragma unroll
    for (int ph = 0; ph < 4; ++ph) {
        const int plr = ph * 16 + (tid >> 4);
        const int p = p0 + plr;
        const int c = (tid & 15) * 2;
        if (p < NPIX) {
            const unsigned int pk = (unsigned int)f2bf(tile[plr][c]) |
                                    ((unsigned int)f2bf(tile[plr][c + 1]) << 16);
            *(unsigned int*)(xbT + (size_t)p * IN_CH + c0 + c) = pk;
        }
    }
}

// ---------- prep 2: conv_w (3969,1024) fp32 -> Wr (4096,1024) bf16, n = bin*82+t ----
__global__ __launch_bounds__(256) void prep_w(const float* __restrict__ conv_w,
                                              ushortT* __restrict__ Wr) {
    const int row = blockIdx.x;           // n
    const int bin = row / COLB;
    const int t   = row - bin * COLB;
    const int c   = threadIdx.x * 4;
    uint2 pk; pk.x = 0; pk.y = 0;
    if (bin < NBINS && t < NT) {
        const float4 v = *(const float4*)(conv_w + ((size_t)(t * NBINS + bin)) * IN_CH + c);
        pk.x = (unsigned int)f2bf(v.x) | ((unsigned int)f2bf(v.y) << 16);
        pk.y = (unsigned int)f2bf(v.z) | ((unsigned int)f2bf(v.w) << 16);
    }
    *(uint2*)(Wr + (size_t)row * IN_CH + c) = pk;
}

// ---------- GEMM: sm[pix][4018] bf16 = xbT(10000,1024) @ Wr(4096,1024)^T ------------
// m97 structure: 128x128 tile, BK=32, global_load_lds width 16, 4 waves (2x2),
// each wave 64x64 via 4x4 grid of 16x16x32 bf16 MFMA.
__global__ __launch_bounds__(256) void gemm_sm(const ushortT* __restrict__ xbT,
                                               const ushortT* __restrict__ Wr,
                                               ushortT* __restrict__ sm) {
    __shared__ ushortT a_lds[128 * 32];   // [row][k], contiguous (DMA layout)
    __shared__ ushortT b_lds[128 * 32];
    const int tid  = threadIdx.x;
    const int lane = tid & 63;
    const int w    = tid >> 6;
    const int wm   = w & 1;
    const int wn   = w >> 1;
    const int n0   = blockIdx.x * 128;    // 0..31 tiles
    const int p0   = blockIdx.y * 128;    // 0..78 tiles

    // staging geometry: wave w covers rows w*32 + i*16 + (lane>>2), 16B at (lane&3)*8
    const int srow0 = w * 32 + (lane >> 2);
    const int scol  = (lane & 3) * 8;
    int ap0 = p0 + srow0;      if (ap0 > NPIX - 1) ap0 = NPIX - 1;
    int ap1 = p0 + srow0 + 16; if (ap1 > NPIX - 1) ap1 = NPIX - 1;
    const ushortT* ag0 = xbT + (size_t)ap0 * IN_CH + scol;
    const ushortT* ag1 = xbT + (size_t)ap1 * IN_CH + scol;
    const ushortT* bg0 = Wr + (size_t)(n0 + srow0) * IN_CH + scol;
    const ushortT* bg1 = Wr + (size_t)(n0 + srow0 + 16) * IN_CH + scol;
    ushortT* al0 = a_lds + (w * 32) * 32;
    ushortT* al1 = a_lds + (w * 32 + 16) * 32;
    ushortT* bl0 = b_lds + (w * 32) * 32;
    ushortT* bl1 = b_lds + (w * 32 + 16) * 32;

    const int m_lane = lane & 15;
    const int k0     = (lane >> 4) * 8;

    f32x4 acc[4][4];
#pragma unroll
    for (int mt = 0; mt < 4; ++mt)
#pragma unroll
        for (int nt = 0; nt < 4; ++nt) acc[mt][nt] = (f32x4){0.f, 0.f, 0.f, 0.f};

    for (int kc = 0; kc < IN_CH / 32; ++kc) {
        __syncthreads();                 // prior frag reads done before overwrite
        gld_lds16(ag0, al0);
        gld_lds16(ag1, al1);
        gld_lds16(bg0, bl0);
        gld_lds16(bg1, bl1);
        ag0 += 32; ag1 += 32; bg0 += 32; bg1 += 32;
        __syncthreads();                 // drains vmcnt (DMA) before frag reads

        bf16x8 af[4], bf[4];
#pragma unroll
        for (int mt = 0; mt < 4; ++mt)
            af[mt] = *(const bf16x8*)(a_lds + (wm * 64 + mt * 16 + m_lane) * 32 + k0);
#pragma unroll
        for (int nt = 0; nt < 4; ++nt)
            bf[nt] = *(const bf16x8*)(b_lds + (wn * 64 + nt * 16 + m_lane) * 32 + k0);
#pragma unroll
        for (int mt = 0; mt < 4; ++mt)
#pragma unroll
            for (int nt = 0; nt < 4; ++nt)
                acc[mt][nt] = __builtin_amdgcn_mfma_f32_16x16x32_bf16(af[mt], bf[nt], acc[mt][nt], 0, 0, 0);
    }

    // epilogue: C row = pix (A side), col = n (B side); store bf16 into sm
    const int prow_base = p0 + wm * 64 + (lane >> 4) * 4;
    const int ncol_base = n0 + wn * 64 + m_lane;
#pragma unroll
    for (int mt = 0; mt < 4; ++mt) {
#pragma unroll
        for (int rg = 0; rg < 4; ++rg) {
            const int p = prow_base + mt * 16 + rg;
            if (p < NPIX) {
#pragma unroll
                for (int nt = 0; nt < 4; ++nt) {
                    const int n = ncol_base + nt * 16;
                    if (n < NCOL) sm[(size_t)p * SMSTR + n] = f2bf(acc[mt][nt][rg]);
                }
            }
        }
    }
}

// ---------- pooling: one block per region; tap (bin,i,j) reads 82 bf16 @ pix*4018+bin*82
__global__ __launch_bounds__(256) void pool_kernel(const ushortT* __restrict__ sm,
                                                   const float* __restrict__ regions,
                                                   const float* __restrict__ conv_b,
                                                   float* __restrict__ out) {
    __shared__ int   pofs[784];
    __shared__ float pw[784];
    __shared__ int   rowo[28]; __shared__ float roww[28];
    __shared__ int   coli[28]; __shared__ float colw[28];
    __shared__ float part[4][COLB];
    const int tid = threadIdx.x;
    const int r = blockIdx.x;

    if (tid < 28) {
        const float4 reg = *(const float4*)(regions + (size_t)r * 4);
        const float top = (reg.x - reg.z * 0.5f) * (float)HH;
        const float bh  = reg.z * ((float)HH / (float)KGRID);
        const int u = tid >> 2, i = tid & 3;
        const int s = i >> 1, hi = i & 1;
        float y = top + ((float)u + ((float)s + 0.5f) * 0.5f) * bh;
        y = fminf(fmaxf(y, 0.0f), (float)(HH - 1));
        const float y0f = floorf(y);
        const int y0 = (int)y0f;
        const float wy1 = y - y0f;
        rowo[tid] = (hi ? min(y0 + 1, HH - 1) : y0) * WW;
        roww[tid] = hi ? wy1 : (1.0f - wy1);
    } else if (tid >= 32 && tid < 60) {
        const float4 reg = *(const float4*)(regions + (size_t)r * 4);
        const float left = (reg.y - reg.w * 0.5f) * (float)WW;
        const float bw   = reg.w * ((float)WW / (float)KGRID);
        const int idx = tid - 32;
        const int v = idx >> 2, j = idx & 3;
        const int s = j >> 1, hi = j & 1;
        float xx = left + ((float)v + ((float)s + 0.5f) * 0.5f) * bw;
        xx = fminf(fmaxf(xx, 0.0f), (float)(WW - 1));
        const float x0f = floorf(xx);
        const int x0 = (int)x0f;
        const float wx1 = xx - x0f;
        coli[idx] = hi ? min(x0 + 1, WW - 1) : x0;
        colw[idx] = hi ? wx1 : (1.0f - wx1);
    }
    __syncthreads();
    for (int tt = tid; tt < 784; tt += 256) {
        const int bin = tt >> 4, tap = tt & 15;
        const int u = bin / KGRID, v = bin - u * KGRID;
        const int i = tap >> 2, j = tap & 3;
        const int pix = rowo[u * 4 + i] + coli[v * 4 + j];
        pofs[tt] = pix * SMSTR + bin * COLB;
        pw[tt]   = roww[u * 4 + i] * colw[v * 4 + j] * (1.0f / 196.0f);
    }
    __syncthreads();
    const int lane = tid & 63, w = tid >> 6;
    if (lane < COLB / 2) {               // 41 lanes, 2 channels each
        float accx = 0.f, accy = 0.f;
        const int l2 = lane * 2;
#pragma unroll 4
        for (int tt = w; tt < 784; tt += 4) {
            const unsigned int v = *(const unsigned int*)(sm + pofs[tt] + l2);
            const float wt = pw[tt];
            accx += wt * __builtin_bit_cast(float, v << 16);
            accy += wt * __builtin_bit_cast(float, v & 0xffff0000u);
        }
        part[w][l2] = accx; part[w][l2 + 1] = accy;
    }
    __syncthreads();
    if (tid < NT) {
        const float sv = part[0][tid] + part[1][tid] + part[2][tid] + part[3][tid];
        float b = 0.f;
        for (int bin = 0; bin < NBINS; ++bin) b += conv_b[tid * NBINS + bin];
        out[(size_t)r * NT + tid] = sv + b * (1.0f / (float)NBINS);
    }
}

// =======================  fallback path (round-1 kernel)  ==========================
__global__ __launch_bounds__(256) void xpose_kernel(const float* __restrict__ x,
                                                    float* __restrict__ xt) {
    __shared__ float tile[32][33];
    const int p0 = blockIdx.x * 32;
    const int c0 = blockIdx.y * 32;
    const int tx = threadIdx.x;
    const int ty = threadIdx.y;
#pragma unroll
    for (int k = 0; k < 32; k += 8) {
        const int p = p0 + tx;
        if (p < NPIX) tile[ty + k][tx] = x[(size_t)(c0 + ty + k) * NPIX + p];
    }
    __syncthreads();
#pragma unroll
    for (int k = 0; k < 32; k += 8) {
        const int p = p0 + ty + k;
        if (p < NPIX) xt[(size_t)p * IN_CH + (c0 + tx)] = tile[tx][ty + k];
    }
}

template <bool XPOSED>
__global__ __launch_bounds__(256) void psroi_kernel(
    const float* __restrict__ xsrc, const float* __restrict__ regions,
    const float* __restrict__ conv_w, const float* __restrict__ conv_b,
    float* __restrict__ out) {
    __shared__ float w_lds[32 * 96];
    __shared__ float g_lds[32 * 64];
    __shared__ int   rowoff[64][4];
    __shared__ float rowwf[64][4];
    __shared__ int   colidx[64][4];
    __shared__ float colwf[64][4];
    const int tid = threadIdx.x;
    const int bin = blockIdx.x >> 4;
    const int rg  = blockIdx.x & 15;
    const int u = bin / KGRID, v = bin % KGRID;
    const int r0 = rg * 64;
    if (tid < 64) {
        const float4 reg = *(const float4*)(regions + (size_t)(r0 + tid) * 4);
        const float top  = (reg.x - reg.z * 0.5f) * (float)HH;
        const float left = (reg.y - reg.w * 0.5f) * (float)WW;
        const float bh = reg.z * ((float)HH / (float)KGRID);
        const float bw = reg.w * ((float)WW / (float)KGRID);
        const float scale = 1.0f / 196.0f;
#pragma unroll
        for (int s = 0; s < 2; s++) {
            const float off = (s + 0.5f) * 0.5f;
            float yy = top + ((float)u + off) * bh;
            yy = fminf(fmaxf(yy, 0.0f), (float)(HH - 1));
            const float y0f = floorf(yy);
            const int y0 = (int)y0f;
            const float wy1 = yy - y0f;
            rowoff[tid][2 * s] = y0 * WW;
            rowoff[tid][2 * s + 1] = min(y0 + 1, HH - 1) * WW;
            rowwf[tid][2 * s] = (1.0f - wy1) * scale;
            rowwf[tid][2 * s + 1] = wy1 * scale;
            float xx = left + ((float)v + off) * bw;
            xx = fminf(fmaxf(xx, 0.0f), (float)(WW - 1));
            const float x0f = floorf(xx);
            const int x0 = (int)x0f;
            const float wx1 = xx - x0f;
            colidx[tid][2 * s] = x0;
            colidx[tid][2 * s + 1] = min(x0 + 1, WW - 1);
            colwf[tid][2 * s] = 1.0f - wx1;
            colwf[tid][2 * s + 1] = wx1;
        }
    }
    const int ri = tid & 15, tq = tid >> 4, rb = tid >> 2, cq = tid & 3;
    float acc[4][6];
#pragma unroll
    for (int m = 0; m < 4; m++)
#pragma unroll
        for (int k = 0; k < 6; k++) acc[m][k] = 0.0f;
    for (int chunk = 0; chunk < IN_CH / 32; chunk++) {
        const int c0 = chunk * 32;
        __syncthreads();
#pragma unroll
        for (int it = 0; it < 12; it++) {
            const int idx = it * 256 + tid;
            const int t = idx >> 5, c = idx & 31;
            float val = 0.0f;
            if (t < NT) val = conv_w[(size_t)(t * NBINS + bin) * IN_CH + c0 + c];
            w_lds[c * 96 + t] = val;
        }
        const int cbase = c0 + cq * 8;
        float g8[8];
#pragma unroll
        for (int cc = 0; cc < 8; cc++) g8[cc] = 0.0f;
#pragma unroll
        for (int i = 0; i < 4; i++) {
            const int ro = rowoff[rb][i];
            const float wy = rowwf[rb][i];
#pragma unroll
            for (int j = 0; j < 4; j++) {
                const int pix = ro + colidx[rb][j];
                const float wv = wy * colwf[rb][j];
                if (XPOSED) {
                    const float4* p = (const float4*)(xsrc + (size_t)pix * IN_CH + cbase);
                    const float4 a = p[0]; const float4 b = p[1];
                    g8[0] += wv * a.x; g8[1] += wv * a.y; g8[2] += wv * a.z; g8[3] += wv * a.w;
                    g8[4] += wv * b.x; g8[5] += wv * b.y; g8[6] += wv * b.z; g8[7] += wv * b.w;
                } else {
#pragma unroll
                    for (int cc = 0; cc < 8; cc++)
                        g8[cc] += wv * xsrc[(size_t)(cbase + cc) * NPIX + pix];
                }
            }
        }
#pragma unroll
        for (int cc = 0; cc < 8; cc++) g_lds[(cq * 8 + cc) * 64 + rb] = g8[cc];
        __syncthreads();
#pragma unroll 4
        for (int c = 0; c < 32; c++) {
            float wv[6];
#pragma unroll
            for (int k = 0; k < 6; k++) wv[k] = w_lds[c * 96 + tq * 6 + k];
            const float4 gq = *(const float4*)&g_lds[c * 64 + ri * 4];
            const float gm[4] = {gq.x, gq.y, gq.z, gq.w};
#pragma unroll
            for (int m = 0; m < 4; m++)
#pragma unroll
                for (int k = 0; k < 6; k++) acc[m][k] += gm[m] * wv[k];
        }
    }
    const float invK2 = 1.0f / 49.0f;
#pragma unroll
    for (int k = 0; k < 6; k++) {
        const int t = tq * 6 + k;
        if (t < NT) {
            const float bterm = conv_b[t * NBINS + bin] * invK2;
#pragma unroll
            for (int m = 0; m < 4; m++) {
                const int rr = r0 + ri * 4 + m;
                atomicAdd(&out[(size_t)rr * NT + t], acc[m][k] + bterm);
            }
        }
    }
}

extern "C" void kernel_launch(void* const* d_in, const int* in_sizes, int n_in,
                              void* d_out, int out_size, void* d_ws, size_t ws_size,
                              hipStream_t stream) {
    const float* x       = (const float*)d_in[0];
    const float* regions = (const float*)d_in[1];
    const float* conv_w  = (const float*)d_in[2];
    const float* conv_b  = (const float*)d_in[3];
    float* out = (float*)d_out;

    const size_t sz_xbT = (size_t)NPIX * IN_CH * 2;          // 20,480,000
    const size_t sz_Wr  = (size_t)NPADW * IN_CH * 2;         //  8,388,608
    const size_t sz_sm  = (size_t)NPIX * SMSTR * 2;          // 80,360,000
    const size_t need   = sz_xbT + sz_Wr + sz_sm;            // 109,228,608

    if (ws_size >= need) {
        ushortT* xbT = (ushortT*)d_ws;
        ushortT* Wr  = (ushortT*)((char*)d_ws + sz_xbT);
        ushortT* sm  = (ushortT*)((char*)d_ws + sz_xbT + sz_Wr);
        prep_x<<<dim3((NPIX + 63) / 64, IN_CH / 32), 256, 0, stream>>>(x, xbT);
        prep_w<<<dim3(NPADW), 256, 0, stream>>>(conv_w, Wr);
        gemm_sm<<<dim3(NPADW / 128, (NPIX + 127) / 128), 256, 0, stream>>>(xbT, Wr, sm);
        pool_kernel<<<dim3(NREG), 256, 0, stream>>>(sm, regions, conv_b, out);
    } else {
        hipMemsetAsync(out, 0, (size_t)out_size * sizeof(float), stream);
        const size_t xt_bytes = (size_t)NPIX * IN_CH * sizeof(float);
        const dim3 mainGrid(NBINS * 16);
        if (ws_size >= xt_bytes) {
            float* xt = (float*)d_ws;
            xpose_kernel<<<dim3((NPIX + 31) / 32, IN_CH / 32), dim3(32, 8), 0, stream>>>(x, xt);
            psroi_kernel<true><<<mainGrid, 256, 0, stream>>>(xt, regions, conv_w, conv_b, out);
        } else {
            psroi_kernel<false><<<mainGrid, 256, 0, stream>>>(x, regions, conv_w, conv_b, out);
        }
    }
}